// Round 4
// baseline (69.714 us; speedup 1.0000x reference)
//
#include <hip/hip_runtime.h>
#include <math.h>

#ifndef __has_builtin
#define __has_builtin(x) 0
#endif

#define GRIDC  32          // cells per axis (256 px / 8 px)
#define NCELL  1024
#define CSHIFT 3           // 8 px cells
#define RAD    4           // +-4 cells => all nodes within 32 px included.
                           // RAD must stay 4: with RAD=3 a worst-case query
                           // (nearest node ~13px, sigma^2=1) keeps r ~ e^-85
                           // while dropping r ~ e^-58 -> output corrupted.
                           // At RAD=4 dropped r <= e^-102 << any kept term.
#define NPAD   2056        // 2048 nodes + 8 pad entries so the software
                           // pipeline can prefetch sA[k+4] unconditionally
                           // (junk is rotated out, never computed on).

__device__ __forceinline__ float fast_exp2(float x) {
#if __has_builtin(__builtin_amdgcn_exp2f)
    return __builtin_amdgcn_exp2f(x);
#else
    return exp2f(x);
#endif
}

__device__ __forceinline__ int cell_of(int x, int y) {
    int cx = x >> CSHIFT; cx = cx < 0 ? 0 : (cx > GRIDC - 1 ? GRIDC - 1 : cx);
    int cy = y >> CSHIFT; cy = cy < 0 ? 0 : (cy > GRIDC - 1 ? GRIDC - 1 : cy);
    return (cy << 5) + cx;
}

// ---------------------------------------------------------------------------
// Single fused kernel, ONE dispatch. Measured decomposition (rounds 0-3):
// timed region ~= 40us ws-poison fill (84% HBM peak, harness) + ~22-27us
// harness restore dispatches/graph overhead + THIS KERNEL (~3-6us). So this
// round is pure critical-path latency surgery on the kernel:
//   - ALL global loads (pattern, sig, 3 W2 rows, X) issued in the prologue,
//     before any barrier -> ~900cyc HBM cold latency overlaps phase 1a-1c
//     instead of serializing after 4 barriers in the old phase 1d.
//   - phase 2 prefetches the NEXT row's sst[k0]/sst[k1] pair one row ahead
//     -> ~120cyc LDS latency hides under the current row's inner loop.
//   - dead barrier removed (wsum reads vs sst writes touch disjoint arrays).
// Layout unchanged from round 3 (best so far): 512 thr, 128 queries/block,
// 4 consecutive lanes/query, padded-LDS 1-deep pipeline, DPP reduction,
// contiguous 48-dword wave store. LDS ~52.6 KB -> 2 blocks/CU, 16 waves/CU.
// ---------------------------------------------------------------------------
__global__ __launch_bounds__(512, 4) void rbf_g4(const int* __restrict__ X,
        const int* __restrict__ pat, const float* __restrict__ W2,
        const float* __restrict__ sig, float* __restrict__ out, int N, int P) {
    __shared__ float4 sA[NPAD];        // {px, py, s, w0}   32.9 KB
    __shared__ float2 sB[NPAD];        // {w1, w2}          16.4 KB
    __shared__ int    sst[NCELL + 1];  // counts -> starts   4.1 KB
    __shared__ int    wsum[8];

    const int tid  = threadIdx.x;
    const int lane = tid & 63;
    const int wv   = tid >> 6;

    // ---- Prologue: issue ALL global loads before any barrier ----
    const int g   = tid >> 2;          // phase-2 group 0..127
    const int l4  = tid & 3;           // lane within group
    const int n   = blockIdx.x * 128 + g;
    const bool act = n < N;
    int2 qxy = make_int2(0, 0);
    if (act) qxy = ((const int2*)X)[n];            // 4-lane broadcast read

    int2  nxy[4];
    float nsig[4], nw0[4], nw1[4], nw2[4];
#pragma unroll
    for (int j = 0; j < 4; ++j) {
        int p = j * 512 + tid;
        if (p < P) {
            nxy[j]  = ((const int2*)pat)[p];
            nsig[j] = sig[p];
            nw0[j]  = W2[p];
            nw1[j]  = W2[P + p];
            nw2[j]  = W2[2 * P + p];
        } else {
            nxy[j] = make_int2(-1, -1);
        }
    }

    // ---- Phase 1a: zero counts (overlaps global-load latency) ----
    for (int i = tid; i < NCELL + 1; i += 512) sst[i] = 0;
    __syncthreads();

    // ---- Phase 1b: histogram (waits only on the pattern loads) ----
    int cellr[4], slotr[4];
#pragma unroll
    for (int j = 0; j < 4; ++j) {
        cellr[j] = -1;
        if (j * 512 + tid < P) {
            int c = cell_of(nxy[j].x, nxy[j].y);
            cellr[j] = c;
            slotr[j] = atomicAdd(&sst[c], 1);
        }
    }
    __syncthreads();

    // ---- Phase 1c: exclusive scan of 1024 counts (thread owns 2 cells) ----
    const int c0 = sst[2 * tid], c1 = sst[2 * tid + 1];
    int sum = c0 + c1;
    int incl = sum;
#pragma unroll
    for (int off = 1; off < 64; off <<= 1) {
        int t = __shfl_up(incl, off);
        if (lane >= off) incl += t;
    }
    if (lane == 63) wsum[wv] = incl;
    __syncthreads();
    int base = 0;
#pragma unroll
    for (int w = 0; w < 8; ++w) base += (w < wv) ? wsum[w] : 0;
    const int excl0 = base + incl - sum;        // exclusive start of cell 2*tid
    // NOTE: no barrier here — wsum reads vs sst writes are disjoint arrays,
    // and all sst reads (c0,c1) happened before the previous barrier.
    sst[2 * tid + 0] = excl0;
    sst[2 * tid + 1] = excl0 + c0;
    if (tid == 511) sst[NCELL] = excl0 + c0 + c1;
    __syncthreads();

    // ---- Phase 1d: scatter node records (register-staged, no new loads) ----
#pragma unroll
    for (int j = 0; j < 4; ++j) {
        if (cellr[j] >= 0) {
            int pos = sst[cellr[j]] + slotr[j];
            sA[pos] = make_float4((float)nxy[j].x, (float)nxy[j].y,
                                  -0.7213475204444817f / nsig[j], nw0[j]);
            sB[pos] = make_float2(nw1[j], nw2[j]);
        }
    }
    __syncthreads();

    // ---- Phase 2: 4 consecutive lanes per query, one pass ----
    float den = 0.f, acc0 = 0.f, acc1 = 0.f, acc2 = 0.f;
    if (act) {
        const float xf = (float)qxy.x, yf = (float)qxy.y;
        int cx = qxy.x >> CSHIFT; cx = cx < 0 ? 0 : (cx > GRIDC - 1 ? GRIDC - 1 : cx);
        int cy = qxy.y >> CSHIFT; cy = cy < 0 ? 0 : (cy > GRIDC - 1 ? GRIDC - 1 : cy);
        const int x0 = cx - RAD < 0 ? 0 : cx - RAD;
        const int x1 = cx + RAD > GRIDC - 1 ? GRIDC - 1 : cx + RAD;
        const int y0 = cy - RAD < 0 ? 0 : cy - RAD;
        const int y1 = cy + RAD > GRIDC - 1 ? GRIDC - 1 : cy + RAD;
        // row-ahead pipeline for the sst window bounds (~120cyc LDS latency
        // hides under the current row's inner loop)
        int row = y0 << 5;
        int k0 = sst[row + x0];
        int k1 = sst[row + x1 + 1];
        for (int gy = y0; gy <= y1; ++gy) {
            int nk0 = 0, nk1 = 0;
            if (gy < y1) {
                int nrow = (gy + 1) << 5;
                nk0 = sst[nrow + x0];          // issued before inner loop
                nk1 = sst[nrow + x1 + 1];
            }
            int k = k0 + l4;
            if (k < k1) {
                // 1-deep pipeline, NO clamp: prefetch k+4 from padded LDS
                float4 a = sA[k];
                float2 b = sB[k];
                for (; k < k1; k += 4) {
                    float4 an = sA[k + 4];
                    float2 bn = sB[k + 4];
                    float dx = xf - a.x;
                    float dy = yf - a.y;
                    float rr = fast_exp2(fmaf(dy, dy, dx * dx) * a.z);
                    den  += rr;
                    acc0 = fmaf(rr, a.w, acc0);
                    acc1 = fmaf(rr, b.x, acc1);
                    acc2 = fmaf(rr, b.y, acc2);
                    a = an; b = bn;
                }
            }
            k0 = nk0; k1 = nk1;
        }
    }

    // 4-lane reduction (strides 1/2 -> DPP-cheap; partners share n)
    den  += __shfl_xor(den,  1); acc0 += __shfl_xor(acc0, 1);
    acc1 += __shfl_xor(acc1, 1); acc2 += __shfl_xor(acc2, 1);
    den  += __shfl_xor(den,  2); acc0 += __shfl_xor(acc0, 2);
    acc1 += __shfl_xor(acc1, 2); acc2 += __shfl_xor(acc2, 2);

    // contiguous wave store: lane l4 in {0,1,2} writes out[3n+l4]
    if (act && l4 < 3) {
        float inv = 1.0f / den;
        float v = (l4 == 0) ? acc0 : ((l4 == 1) ? acc1 : acc2);
        out[3 * n + l4] = v * inv;
    }
}

// ---------------------------------------------------------------------------
// Generic fallback (unexpected sizes): brute-force N x P sweep.
// ---------------------------------------------------------------------------
__global__ void pack_nodes(const int* __restrict__ pat, const float* __restrict__ W2,
                           const float* __restrict__ sigmaSq, float* __restrict__ nodes,
                           int P) {
    int p = blockIdx.x * blockDim.x + threadIdx.x;
    if (p >= P) return;
    float* q = nodes + 8 * (size_t)p;
    q[0] = (float)pat[2 * p];
    q[1] = (float)pat[2 * p + 1];
    q[2] = -0.7213475204444817f / sigmaSq[p];
    q[3] = W2[p];
    q[4] = W2[P + p];
    q[5] = W2[2 * P + p];
    q[6] = 0.0f;
    q[7] = 0.0f;
}

__global__ __launch_bounds__(256) void rbf_main_dyn(const int* __restrict__ X,
                                                    const float* __restrict__ nodes,
                                                    float* __restrict__ outp,
                                                    int N, int P) {
    int n = blockIdx.x * 256 + threadIdx.x;
    if (n >= N) return;
    float xn = (float)X[2 * n], yn = (float)X[2 * n + 1];
    float den = 0.f, a0 = 0.f, a1 = 0.f, a2 = 0.f;
    for (int j = 0; j < P; ++j) {
        const float* q = nodes + (size_t)j * 8;
        float dx = xn - q[0], dy = yn - q[1];
        float r = fast_exp2(fmaf(dy, dy, dx * dx) * q[2]);
        den += r;
        a0 = fmaf(r, q[3], a0);
        a1 = fmaf(r, q[4], a1);
        a2 = fmaf(r, q[5], a2);
    }
    outp[3 * n + 0] = a0 / den;
    outp[3 * n + 1] = a1 / den;
    outp[3 * n + 2] = a2 / den;
}

extern "C" void kernel_launch(void* const* d_in, const int* in_sizes, int n_in,
                              void* d_out, int out_size, void* d_ws, size_t ws_size,
                              hipStream_t stream) {
    const int*   X   = (const int*)d_in[0];
    const int*   pat = (const int*)d_in[1];
    const float* W2  = (const float*)d_in[2];
    const float* sig = (const float*)d_in[3];
    float*       out = (float*)d_out;

    const int N = in_sizes[0] / 2;
    const int P = in_sizes[3];

    if (P <= 2048 && out_size == 3 * N) {
        rbf_g4<<<dim3((N + 127) / 128), dim3(512), 0, stream>>>(
            X, pat, W2, sig, out, N, P);
    } else {
        float* nodes = (float*)d_ws;
        pack_nodes<<<dim3((P + 255) / 256), dim3(256), 0, stream>>>(pat, W2, sig, nodes, P);
        rbf_main_dyn<<<dim3((N + 255) / 256), dim3(256), 0, stream>>>(X, nodes, out, N, P);
    }
}